// Round 16
// baseline (352.158 us; speedup 1.0000x reference)
//
#include <hip/hip_runtime.h>
#include <math.h>

// Problem constants
#define NB 2
#define NC 256
#define CG 16
#define HH 192
#define WW 192
#define HO 190
#define PP 144

typedef float v2f __attribute__((ext_vector_type(2)));

// LDS: 5684 floats = 22736 B -> 7 blocks/CU (was 29392 B -> 5).
// Band area: 29 rows x 49 float4-slots (196 floats/row: slots [0..3]=pads,
//   [4..195]=data, data col c at 4+c). Staged LINEARLY by global_load_lds;
//   pad-slot lanes load a harmless dup; pads re-zeroed after the drain.
//   Thread v's window = slots v+2..v+6; b64 reads at even base bb=(v+2)&~1.
// Epilogue: edge rows 0..11, row 12 = zero guard (0..2547);
//   red2[96][25] at 2548 (2548..4947); ebuf[2][25] at 4948.
#define SMEM_FLOATS 5684

#define GLD16(GP, LP)                                                         \
    __builtin_amdgcn_global_load_lds(                                         \
        (const __attribute__((address_space(1))) void*)(GP),                  \
        (__attribute__((address_space(3))) void*)(LP), 16, 0, 0)

// ---------------------------------------------------------------------------
// Kernel 1: correlation-decomposed Gram. Bit-identical gram vs rounds 1-14:
// u runs 2..189 sequentially with identical per-step FMA order; the reduce's
// first step (192->96) becomes a publish/merge pair computing the same
// cw_low + cw_high (IEEE add commutative bitwise).
// THIS ROUND: LDS diet for occupancy. 24-step bands (29-row area) +
// red2[96][25] two-phase reduce -> 22.7 KB -> 7 blocks/CU = 21 waves (was
// 5/15; r14 measured VALUBusy 43% = latency-bound). Low half recomputes cw
// at merge (no +25 VGPR). Staging = r14 winner: global_load_lds, linear
// dest, one drain/band. Compute = r12: dj-pair pk packing, b64 window
// reads, 6-phase pipelined ring, 6-deep global ring, XCD swizzle.
// ---------------------------------------------------------------------------
__global__ __launch_bounds__(192, 2) void gram_kernel(const float* __restrict__ x,
                                                      double* __restrict__ gram)
{
    __shared__ __align__(16) float smem[SMEM_FLOATS];
    float* const red2 = smem + 2548;          // [96][25]
    float* const ebuf = smem + 4948;          // [2][25]

    const int v = threadIdx.x;                // column 0..191
    const int p = v & 1;                      // window parity: dj = i - p
    const int bb = (v + 2) & ~1;              // even b64 base slot

    // XCD-clustered decode: bid%8 = intended XCD; half-group hg (36 blocks)
    // pinned to XCD hg%8. Bijective over 2304 blocks.
    const int bid = blockIdx.x;
    const int vx = bid & 7;
    const int tq = bid >> 3;                  // 0..287
    const int idxw = tq / 36;                 // 0..7
    const int rr0 = tq - idxw * 36;           // 0..35
    const int hg = idxw * 8 + vx;             // 0..63
    const int bg = hg >> 1;
    int r = rr0 + 36 * (hg & 1);              // 0..71
    int c2 = 0;
    while (r >= (c2 + 2) / 2) { r -= (c2 + 2) / 2; ++c2; }
    const int c1a = 2 * r;
    int c1b = 2 * r + 1;
    const bool bval = (c1b <= c2);
    if (!bval) c1b = c2;
    const int b = bg >> 4, g = bg & 15;

    const float* __restrict__ xa  = x + ((size_t)(b * NC + g * CG + c1a)) * (HH * WW);
    const float* __restrict__ xb  = x + ((size_t)(b * NC + g * CG + c1b)) * (HH * WW);
    const float* __restrict__ x2g = x + ((size_t)(b * NC + g * CG + c2 )) * (HH * WW);

    // accumulators: lanes = window positions (2*pr, 2*pr+1); dj = pos - p.
    v2f midA[15], midB[15];                   // [k*3 + pr]
#pragma unroll
    for (int o = 0; o < 15; ++o) { midA[o] = (v2f){0.f, 0.f}; midB[o] = (v2f){0.f, 0.f}; }

    v2f win[6][3];                            // slot s: local row L (L%6==s), 3 pairs
    float ca[6], cb[6];                       // ca[(u-2)%6] holds xa row u
#pragma unroll
    for (int k = 0; k < 6; ++k) {             // rows 2..7
        ca[k] = xa[(size_t)(2 + k) * WW + v];
        cb[k] = xb[(size_t)(2 + k) * WW + v];
    }

    const float* pa = xa + (size_t)8 * WW + v;   // refill base (row ubase+6)
    const float* pb = xb + (size_t)8 * WW + v;
    int lds_off;                              // float idx of WPF row b64 base

// One u-step. P = phase = LS%6 (compile-time). Consumes ca/cb[P] (row u) and
// win slots (P+kk)%6 (local rows LS..LS+4, loaded >=1 step earlier).
//   WPF: window row local LS+5 -> slot (P+5)%6: 3 x ds_read_b64;
//   GPF: ca/cb[P] <- rows at pa/pb[P*WW] (consumed 6 steps later).
#define USTEP6(P, WPF, GPF)                                                   \
    {                                                                         \
        const float a1 = ca[(P)];                                             \
        const float b1 = cb[(P)];                                             \
        if (GPF) { ca[(P)] = pa[(P) * WW]; cb[(P)] = pb[(P) * WW]; }          \
        if (WPF) {                                                            \
            _Pragma("unroll")                                                 \
            for (int pr = 0; pr < 3; ++pr)                                    \
                win[((P) + 5) % 6][pr] = *(const v2f*)(&smem[lds_off + 2 * pr]); \
        }                                                                     \
        lds_off += 196;                                                       \
        const v2f a2 = (v2f){a1, a1};                                         \
        const v2f b2 = (v2f){b1, b1};                                         \
        _Pragma("unroll")                                                     \
        for (int kk = 0; kk < 5; ++kk) {                                      \
            _Pragma("unroll")                                                 \
            for (int pr = 0; pr < 3; ++pr) {                                  \
                const v2f wv = win[((P) + kk) % 6][pr];                       \
                midA[kk * 3 + pr] = __builtin_elementwise_fma(a2, wv, midA[kk * 3 + pr]); \
                midB[kk * 3 + pr] = __builtin_elementwise_fma(b2, wv, midB[kk * 3 + pr]); \
            }                                                                 \
        }                                                                     \
    }

// Stage rows [ROW0, ...) linearly via global_load_lds (NROUND rounds, last
// round LASTN lanes); drain; re-zero pads of rows 0..28; barrier.
#define STAGE(ROW0, NROUND, LASTN)                                            \
    __syncthreads();                                                          \
    _Pragma("unroll")                                                         \
    for (int rr2 = 0; rr2 < (NROUND); ++rr2) {                                \
        if (rr2 < (NROUND) - 1 || v < (LASTN)) {                              \
            const int slot = rr2 * 192 + v;                                   \
            const int row = slot / 49;                                        \
            const int s49 = slot - row * 49;                                  \
            const int col = (s49 == 0) ? 0 : (s49 - 1) * 4;                   \
            const float* gp2 = x2g + (size_t)((ROW0) + row) * WW + col;       \
            float* lp = smem + (rr2 * 192 + (v & ~63)) * 4;                   \
            GLD16(gp2, lp);                                                   \
        }                                                                     \
    }                                                                         \
    __syncthreads();                                                          \
    if (v < 116) smem[(v >> 2) * 196 + (v & 3)] = 0.f;                        \
    __syncthreads();

    // 7 full bands x 24 steps (u=2..169, stage 29 rows = 1421 slots: 8
    // rounds, last 77) + 20-step tail (u=170..189, stage 24 rows = 1176
    // slots: 7 rounds, last 24). Step LS=23's WPF loads local 28 = next
    // band's local 4 (24%6==0 keeps ring slots aligned) -> bands chain;
    // only band 0 has a prologue.
    for (int band = 0; band < 7; ++band) {
        STAGE(band * 24, 8, 77)

        if (band == 0) {
#pragma unroll
            for (int k = 0; k < 5; ++k)
#pragma unroll
            for (int pr = 0; pr < 3; ++pr)
                win[k][pr] = *(const v2f*)(&smem[k * 196 + bb + 2 * pr]);
        }

        lds_off = 5 * 196 + bb;               // local row 5, this band
        for (int it = 0; it < 4; ++it) {      // rolled: small hot body
            USTEP6(0, 1, 1) USTEP6(1, 1, 1) USTEP6(2, 1, 1)
            USTEP6(3, 1, 1) USTEP6(4, 1, 1) USTEP6(5, 1, 1)
            pa += 6 * WW; pb += 6 * WW;       // next group's refill base
        }
    }
    // tail: u = 170..189 (LS 0..19), rows 168..191 at locals 0..23.
    STAGE(168, 7, 24)
    lds_off = 5 * 196 + bb;
    // LS 0..5 (u 170..175): GPF rows 176..181
    USTEP6(0, 1, 1) USTEP6(1, 1, 1) USTEP6(2, 1, 1)
    USTEP6(3, 1, 1) USTEP6(4, 1, 1) USTEP6(5, 1, 1)
    pa += 6 * WW; pb += 6 * WW;
    // LS 6..11 (u 176..181): GPF rows 182..187
    USTEP6(0, 1, 1) USTEP6(1, 1, 1) USTEP6(2, 1, 1)
    USTEP6(3, 1, 1) USTEP6(4, 1, 1) USTEP6(5, 1, 1)
    pa += 6 * WW; pb += 6 * WW;
    // LS 12..17 (u 182..187): GPF rows 188,189 only (LS<=13)
    USTEP6(0, 1, 1) USTEP6(1, 1, 1) USTEP6(2, 1, 0)
    USTEP6(3, 1, 0) USTEP6(4, 1, 0) USTEP6(5, 1, 0)
    // LS 18,19 (u 188,189): WPF local 23 at LS=18; none at LS=19
    USTEP6(0, 1, 0) USTEP6(1, 0, 0)
#undef USTEP6
#undef STAGE

    // stage edge buffer: buf i<6 -> abs row i-2 (OOB zero), i>=6 -> 188+(i-6).
    // Pads of rows 0..28 zero from tail re-zero; row 12 = zero guard.
    __syncthreads();
    for (int i = 0; i < 12; ++i) {
        const int ar = (i < 6) ? (i - 2) : (188 + i - 6);
        const float val = (ar >= 0 && ar <= 191) ? x2g[(size_t)ar * WW + v] : 0.f;
        smem[i * 196 + 4 + v] = val;
    }
    __syncthreads();

    double* const gp = gram + (size_t)bg * (PP * PP);

// cw for (k=KQ, dj=DJ) at runtime c=CVAL: mid (parity-selected) + edge-row
// corrections. Compile-time register indices; runtime select on p and CVAL.
#define EPI_CW(KQ, DJ, CVAL)                                                  \
    ({                                                                        \
        float ve_, vo_;                                                       \
        { const int pr_ = (DJ) >> 1, ln_ = (DJ) & 1;                          \
          const v2f m_ = ((CVAL) == 0) ? midA[(KQ) * 3 + pr_] : midB[(KQ) * 3 + pr_]; \
          ve_ = ln_ ? m_.y : m_.x; }                                          \
        { const int pr_ = ((DJ) + 1) >> 1, ln_ = ((DJ) + 1) & 1;              \
          const v2f m_ = ((CVAL) == 0) ? midA[(KQ) * 3 + pr_] : midB[(KQ) * 3 + pr_]; \
          vo_ = ln_ ? m_.y : m_.x; }                                          \
        float cw_ = p ? vo_ : ve_;                                            \
        cw_ = fmaf(xra, smem[bufa * 196 + 2 + v + (DJ)], cw_);                \
        cw_ = fmaf(xrb, smem[bufb * 196 + 2 + v + (DJ)], cw_);                \
        cw_;                                                                  \
    })

#pragma unroll
    for (int i1 = 0; i1 < 3; ++i1) {
        const int ra = (i1 == 0) ? 0 : ((i1 == 1) ? 1 : 190);
        const int rb = (i1 == 0) ? 1 : ((i1 == 1) ? 190 : 191);
#pragma unroll
        for (int c = 0; c < 2; ++c) {
            const float* __restrict__ xc = (c == 0) ? xa : xb;
            const float xra = xc[(size_t)ra * WW + v];
            const float xrb = xc[(size_t)rb * WW + v];
            // publish: high half -> red2 rows 0..95; threads 0,1 -> ebuf
            if (v >= 96) {
#pragma unroll
                for (int k = 0; k < 5; ++k) {
                    const int bufa = (ra < 2) ? (ra + k) : (ra + k - 184);
                    const int bufb = (rb < 2) ? (rb + k) : (rb + k - 184);
#pragma unroll
                    for (int dj = 0; dj < 5; ++dj)
                        red2[(v - 96) * 25 + k * 5 + dj] = EPI_CW(k, dj, c);
                }
            } else if (v < 2) {
#pragma unroll
                for (int k = 0; k < 5; ++k) {
                    const int bufa = (ra < 2) ? (ra + k) : (ra + k - 184);
                    const int bufb = (rb < 2) ? (rb + k) : (rb + k - 184);
#pragma unroll
                    for (int dj = 0; dj < 5; ++dj)
                        ebuf[v * 25 + k * 5 + dj] = EPI_CW(k, dj, c);
                }
            }
            __syncthreads();
            float e0 = 0.f, e1 = 0.f, e190 = 0.f, e191 = 0.f;
            if (v < 25) {
                e0   = ebuf[v];
                e1   = ebuf[25 + v];
                e190 = red2[94 * 25 + v];
                e191 = red2[95 * 25 + v];
            }
            __syncthreads();
            // merge (== old s=96 step): red2[v] = cw_high + cw_low
            if (v < 96) {
#pragma unroll
                for (int k = 0; k < 5; ++k) {
                    const int bufa = (ra < 2) ? (ra + k) : (ra + k - 184);
                    const int bufb = (rb < 2) ? (rb + k) : (rb + k - 184);
#pragma unroll
                    for (int dj = 0; dj < 5; ++dj)
                        red2[v * 25 + k * 5 + dj] += EPI_CW(k, dj, c);
                }
            }
            __syncthreads();
            // tree reduce: 96 -> 48 -> ... -> 3 (stride 25: conflict-free)
#pragma unroll
            for (int s = 48; s >= 3; s >>= 1) {
                for (int idx = v; idx < s * 25; idx += 192) {
                    const int vv = idx / 25, o = idx - vv * 25;
                    red2[vv * 25 + o] += red2[(vv + s) * 25 + o];
                }
                __syncthreads();
            }
            if (v < 25 && (c == 0 || bval)) {
                const int di = v / 5 - 2, dj = v - (v / 5) * 5 - 2;
                const int i2 = i1 + di;
                if (i2 >= 0 && i2 <= 2) {
                    const float S = red2[0 * 25 + v] + red2[1 * 25 + v] + red2[2 * 25 + v];
                    const int c1 = (c == 0) ? c1a : c1b;
#pragma unroll
                    for (int j1 = 0; j1 < 3; ++j1) {
                        const int j2 = j1 + dj;
                        if (j2 < 0 || j2 > 2) continue;
                        const float W = S - ((j1 == 0) ? (e190 + e191)
                                          : (j1 == 1) ? (e0 + e191)
                                                      : (e0 + e1));
                        const int pp = c1 * 9 + i1 * 3 + j1;
                        const int qq = c2 * 9 + i2 * 3 + j2;
                        gp[pp * PP + qq] = (double)W;
                        if (c1 != c2) gp[qq * PP + pp] = (double)W;
                    }
                }
            }
            __syncthreads();   // red2 reused by next (i1,c)
        }
    }
#undef EPI_CW
}

// ---------------------------------------------------------------------------
// Kernel 2: per-group argmin (f64 d2, first-min tiebreak), bincount over both
// batches, stable top-3 (smallest index on count ties, matching lax.top_k).
// ---------------------------------------------------------------------------
__global__ __launch_bounds__(320) void topk_kernel(const double* __restrict__ gram,
                                                   float* __restrict__ pf,
                                                   int* __restrict__ pi)
{
    const int g = blockIdx.x;
    __shared__ double sdiag[2][PP];
    __shared__ int counts[PP];
    const int tid = threadIdx.x;
    if (tid < PP) counts[tid] = 0;
    if (tid < 2 * PP) {
        const int b = tid / PP, p = tid % PP;
        const double* gb = gram + (size_t)(b * 16 + g) * (PP * PP);
        sdiag[b][p] = gb[p * PP + p];
    }
    __syncthreads();
    if (tid < 2 * PP) {
        const int b = tid / PP, p = tid % PP;
        const double* row = gram + ((size_t)(b * 16 + g) * PP + p) * PP;
        const double sp = sdiag[b][p];
        double best = 1e300;
        int bi = 0;
        for (int q = 0; q < PP; ++q) {
            if (q == p) continue;
            const double d2 = sp + sdiag[b][q] - 2.0 * row[q];
            if (d2 < best) { best = d2; bi = q; }   // strict < : first occurrence
        }
        atomicAdd(&counts[bi], 1);
    }
    __syncthreads();
    if (tid == 0) {
        int sel[3], cv[3];
        for (int o = 0; o < 3; ++o) {
            int bc = -1, bp = 0;
            for (int p = 0; p < PP; ++p) {
                bool taken = false;
                for (int u = 0; u < o; ++u) if (sel[u] == p) taken = true;
                if (!taken && counts[p] > bc) { bc = counts[p]; bp = p; } // > keeps lowest idx
            }
            sel[o] = bp; cv[o] = bc;
        }
        const int tot = cv[0] + cv[1] + cv[2];
        for (int o = 0; o < 3; ++o) {
            pf[g * 4 + o] = (float)cv[o];
            pi[g * 4 + o] = sel[o];
        }
        pf[g * 4 + 3] = (float)tot;
    }
}

// ---------------------------------------------------------------------------
// Kernel 3: fused scale->floor->fold stencil. t1,t2 = plain f32 muls
// (== __fmul_rn == reference). Division via Markstein 2-fma refinement:
//   rcp = RN32(1/total)  [f64 path; double-rounding safe: 1/total is
//         >=2^-34 rel from any f32 midpoint, f64 error <=2^-53]
//   q0 = t2*rcp; r = fma(-total,q0,t2); qf = fma(r,rcp,q0)
// qf == __fdiv_rn(t2,total): pre-round error ~2^-47 rel, exact quotients
// are >=2^-34 rel from any f32 midpoint (total<=288, t2 24-bit mantissa;
// exact-midpoint impossible: would need 25-bit odd factor in a <2^24 int).
// All operands stay normal (|t2| >= ~2^-66 given input quantization).
// Interior/edge split by BLOCK range in ONE kernel (branch block-uniform).
// ---------------------------------------------------------------------------
template <bool EDGE>
__device__ __forceinline__ void motif_quad(const float* __restrict__ x,
                                           const float* __restrict__ pf,
                                           const int* __restrict__ pi,
                                           float* __restrict__ out,
                                           int b, int ch, int h, int w0)
{
    const int g = ch >> 4;
    const size_t base = ((size_t)(b * NC + ch)) * (HH * WW);
    const float4 xv4 = *(const float4*)(x + base + (size_t)h * WW + w0);
    const float xs[4] = {xv4.x, xv4.y, xv4.z, xv4.w};
    float acc[4] = {0.f, 0.f, 0.f, 0.f};
    const float total = pf[g * 4 + 3];
    const float rcp = (float)(1.0 / (double)total);   // == RN32(1/total)

#pragma unroll
    for (int o = 0; o < 3; ++o) {
        const int p = pi[g * 4 + o];
        const float cff = pf[g * 4 + o];
        const int co = p / 9;
        const int kk = p - co * 9;
        const int io = kk / 3, jo = kk - (kk / 3) * 3;
        const float* Rb = x + ((size_t)(b * NC + g * CG + co)) * (HH * WW);
#pragma unroll
        for (int i = 0; i < 3; ++i) {
            const int ho = h - i;
            bool rowok = true;
            int hr = ho + io;
            if (EDGE) {
                rowok = (ho >= 0) && (ho < HO);
                hr = hr < 0 ? 0 : (hr > HH - 1 ? HH - 1 : hr);
            }
            const float* row = Rb + (size_t)hr * WW;
            float rv[6];
#pragma unroll
            for (int u = 0; u < 6; ++u) {
                int col = w0 - 2 + jo + u;
                if (EDGE) col = col < 0 ? 0 : (col > WW - 1 ? WW - 1 : col);
                rv[u] = row[col];
            }
#pragma unroll
            for (int j = 0; j < 3; ++j)
#pragma unroll
            for (int q = 0; q < 4; ++q) {
                const float r2 = rv[q - j + 2];
                const float t1 = xs[q] * r2;              // == __fmul_rn
                const float t2 = t1 * cff;                // == __fmul_rn
                const float q0 = t2 * rcp;
                const float rr = fmaf(-total, q0, t2);
                const float qf = fmaf(rr, rcp, q0);       // == __fdiv_rn(t2,total)
                const float vfl = floorf(qf);
                if (EDGE) {
                    const int wo = w0 + q - j;
                    const bool ok = rowok && (wo >= 0) && (wo < HO);
                    acc[q] += ok ? vfl : 0.f;
                } else {
                    acc[q] += vfl;
                }
            }
        }
    }
    float4 ov = make_float4(acc[0], acc[1], acc[2], acc[3]);
    *(float4*)(out + base + (size_t)h * WW + w0) = ov;
}

#define NBLK_INT 17296   // 2*256*188*46/256
#define NBLK_EDGE 1136   // 2*256*568/256

__global__ __launch_bounds__(256) void out_kernel(const float* __restrict__ x,
                                                  const float* __restrict__ pf,
                                                  const int* __restrict__ pi,
                                                  float* __restrict__ out)
{
    const int bid = blockIdx.x;
    if (bid < NBLK_INT) {
        // interior: h in [2,189], w4 in [1,46] -> no clamps/masks anywhere.
        const int gid = bid * 256 + threadIdx.x;
        const int w4i = gid % 46;
        int t = gid / 46;
        const int h = 2 + t % 188; t /= 188;
        const int ch = t & 255;
        const int b = t >> 8;
        motif_quad<false>(x, pf, pi, out, b, ch, h, (w4i + 1) * 4);
    } else {
        // edge: 568 quads per (b,ch): h in {0,1,190,191} x all 48 w4, plus
        // h in [2,189] x w4 in {0,47}.
        const int gid = (bid - NBLK_INT) * 256 + threadIdx.x;
        const int e = gid % 568;
        int t = gid / 568;
        const int ch = t & 255;
        const int b = t >> 8;
        int h, w4;
        if (e < 192) {
            const int hs = e / 48;
            h = (hs < 2) ? hs : 188 + hs;     // 0,1,190,191
            w4 = e % 48;
        } else {
            const int e2 = e - 192;
            h = 2 + (e2 >> 1);
            w4 = (e2 & 1) ? 47 : 0;
        }
        motif_quad<true>(x, pf, pi, out, b, ch, h, w4 * 4);
    }
}

// ---------------------------------------------------------------------------
extern "C" void kernel_launch(void* const* d_in, const int* in_sizes, int n_in,
                              void* d_out, int out_size, void* d_ws, size_t ws_size,
                              hipStream_t stream)
{
    const float* x = (const float*)d_in[0];
    float* out = (float*)d_out;

    double* gram = (double*)d_ws;
    const size_t gram_bytes = (size_t)32 * PP * PP * sizeof(double); // 5,308,416 B
    float* pf = (float*)((char*)d_ws + gram_bytes);
    int* pi = (int*)((char*)d_ws + gram_bytes + 256);

    gram_kernel<<<2304, 192, 0, stream>>>(x, gram);
    topk_kernel<<<16, 320, 0, stream>>>(gram, pf, pi);
    out_kernel<<<NBLK_INT + NBLK_EDGE, 256, 0, stream>>>(x, pf, pi, out);
}

// Round 17
// 346.754 us; speedup vs baseline: 1.0156x; 1.0156x over previous
//
#include <hip/hip_runtime.h>
#include <math.h>

// Problem constants
#define NB 2
#define NC 256
#define CG 16
#define HH 192
#define WW 192
#define HO 190
#define PP 144

typedef float v2f __attribute__((ext_vector_type(2)));

// LDS: 7544 floats = 30176 B.
// Band area: 29 rows x 49 float4-slots (196 floats/row: slots [0..3]=pads,
//   [4..195]=data, data col c at 4+c). Staged LINEARLY by global_load_lds;
//   PAD-SLOT LANES ARE PREDICATED OFF (masked lanes don't write LDS), so
//   pads stay zero from a one-time init -> no per-band re-zero/barrier.
//   Thread v's window = slots v+2..v+6; b64 reads at even base bb=(v+2)&~1.
//   GUARD: lanes 190/191's row-28 read touches floats 5684/5685 (one past
//   the band area) -> zeroed once at init, never written before epilogue
//   (fixes r16's latent OOB read past the declared array).
// Epilogue: edge rows 0..11, row 12 = zero guard (0..2547);
//   red2[96] stride 51 at 2548 (2548..7443); ebuf[2][50] at 7444.
#define SMEM_FLOATS 7544

#define GLD16(GP, LP)                                                         \
    __builtin_amdgcn_global_load_lds(                                         \
        (const __attribute__((address_space(1))) void*)(GP),                  \
        (__attribute__((address_space(3))) void*)(LP), 16, 0, 0)

// ---------------------------------------------------------------------------
// Kernel 1: correlation-decomposed Gram. Bit-identical gram vs rounds 1-16:
// identical per-step FMA order; epilogue reduce keeps identical per-element
// pairing/order (publish/merge = old s=96 step, IEEE add commutative).
// THIS ROUND: (a) epilogue consolidated to 3 passes (both c per i1) on a
// [96][51]-strided buffer -> 24 barriers instead of 48 and half the loop
// overhead; (b) pad-slot staging lanes predicated off -> pads stay zero
// from init -> per-band re-zero + barrier removed; (c) OOB guard floats.
// Staging = r14 winner (global_load_lds, linear dest, one drain/band).
// Compute = r12: dj-pair pk packing, b64 window reads, 6-phase pipelined
// ring, 6-deep global ring, XCD swizzle, direct f64 stores.
// ---------------------------------------------------------------------------
__global__ __launch_bounds__(192, 2) void gram_kernel(const float* __restrict__ x,
                                                      double* __restrict__ gram)
{
    __shared__ __align__(16) float smem[SMEM_FLOATS];
    float* const red2 = smem + 2548;          // stride 51, 96 rows
    float* const ebuf = smem + 7444;          // [2][50]

    const int v = threadIdx.x;                // column 0..191
    const int p = v & 1;                      // window parity: dj = i - p
    const int bb = (v + 2) & ~1;              // even b64 base slot

    // XCD-clustered decode: bid%8 = intended XCD; half-group hg (36 blocks)
    // pinned to XCD hg%8. Bijective over 2304 blocks.
    const int bid = blockIdx.x;
    const int vx = bid & 7;
    const int tq = bid >> 3;                  // 0..287
    const int idxw = tq / 36;                 // 0..7
    const int rr0 = tq - idxw * 36;           // 0..35
    const int hg = idxw * 8 + vx;             // 0..63
    const int bg = hg >> 1;
    int r = rr0 + 36 * (hg & 1);              // 0..71
    int c2 = 0;
    while (r >= (c2 + 2) / 2) { r -= (c2 + 2) / 2; ++c2; }
    const int c1a = 2 * r;
    int c1b = 2 * r + 1;
    const bool bval = (c1b <= c2);
    if (!bval) c1b = c2;
    const int b = bg >> 4, g = bg & 15;

    const float* __restrict__ xa  = x + ((size_t)(b * NC + g * CG + c1a)) * (HH * WW);
    const float* __restrict__ xb  = x + ((size_t)(b * NC + g * CG + c1b)) * (HH * WW);
    const float* __restrict__ x2g = x + ((size_t)(b * NC + g * CG + c2 )) * (HH * WW);

    // one-time zeroing: pad slots of rows 0..28 (116 floats) + OOB guards.
    // Staging never writes pads (predicated off) -> these stay zero.
    if (v < 116) smem[(v >> 2) * 196 + (v & 3)] = 0.f;
    else if (v < 118) smem[5568 + v] = 0.f;   // floats 5684, 5685

    // accumulators: lanes = window positions (2*pr, 2*pr+1); dj = pos - p.
    v2f midA[15], midB[15];                   // [k*3 + pr]
#pragma unroll
    for (int o = 0; o < 15; ++o) { midA[o] = (v2f){0.f, 0.f}; midB[o] = (v2f){0.f, 0.f}; }

    v2f win[6][3];                            // slot s: local row L (L%6==s), 3 pairs
    float ca[6], cb[6];                       // ca[(u-2)%6] holds xa row u
#pragma unroll
    for (int k = 0; k < 6; ++k) {             // rows 2..7
        ca[k] = xa[(size_t)(2 + k) * WW + v];
        cb[k] = xb[(size_t)(2 + k) * WW + v];
    }

    const float* pa = xa + (size_t)8 * WW + v;   // refill base (row ubase+6)
    const float* pb = xb + (size_t)8 * WW + v;
    int lds_off;                              // float idx of WPF row b64 base

// One u-step. P = phase = LS%6 (compile-time). Consumes ca/cb[P] (row u) and
// win slots (P+kk)%6 (local rows LS..LS+4, loaded >=1 step earlier).
//   WPF: window row local LS+5 -> slot (P+5)%6: 3 x ds_read_b64;
//   GPF: ca/cb[P] <- rows at pa/pb[P*WW] (consumed 6 steps later).
#define USTEP6(P, WPF, GPF)                                                   \
    {                                                                         \
        const float a1 = ca[(P)];                                             \
        const float b1 = cb[(P)];                                             \
        if (GPF) { ca[(P)] = pa[(P) * WW]; cb[(P)] = pb[(P) * WW]; }          \
        if (WPF) {                                                            \
            _Pragma("unroll")                                                 \
            for (int pr = 0; pr < 3; ++pr)                                    \
                win[((P) + 5) % 6][pr] = *(const v2f*)(&smem[lds_off + 2 * pr]); \
        }                                                                     \
        lds_off += 196;                                                       \
        const v2f a2 = (v2f){a1, a1};                                         \
        const v2f b2 = (v2f){b1, b1};                                         \
        _Pragma("unroll")                                                     \
        for (int kk = 0; kk < 5; ++kk) {                                      \
            _Pragma("unroll")                                                 \
            for (int pr = 0; pr < 3; ++pr) {                                  \
                const v2f wv = win[((P) + kk) % 6][pr];                       \
                midA[kk * 3 + pr] = __builtin_elementwise_fma(a2, wv, midA[kk * 3 + pr]); \
                midB[kk * 3 + pr] = __builtin_elementwise_fma(b2, wv, midB[kk * 3 + pr]); \
            }                                                                 \
        }                                                                     \
    }

// Stage rows [ROW0, ...) linearly via global_load_lds (NROUND rounds, last
// round LASTN lanes). Pad-slot lanes (s49==0) masked off -> pads untouched.
#define STAGE(ROW0, NROUND, LASTN)                                            \
    __syncthreads();                                                          \
    _Pragma("unroll")                                                         \
    for (int rr2 = 0; rr2 < (NROUND); ++rr2) {                                \
        if (rr2 < (NROUND) - 1 || v < (LASTN)) {                              \
            const int slot = rr2 * 192 + v;                                   \
            const int row = slot / 49;                                        \
            const int s49 = slot - row * 49;                                  \
            if (s49 != 0) {                                                   \
                const float* gp2 = x2g + (size_t)((ROW0) + row) * WW + (s49 - 1) * 4; \
                float* lp = smem + (rr2 * 192 + (v & ~63)) * 4;               \
                GLD16(gp2, lp);                                               \
            }                                                                 \
        }                                                                     \
    }                                                                         \
    __syncthreads();

    // 7 full bands x 24 steps (u=2..169, stage 29 rows = 1421 slots: 8
    // rounds, last 77) + 20-step tail (u=170..189, stage 24 rows = 1176
    // slots: 7 rounds, last 24). Step LS=23's WPF loads local 28 = next
    // band's local 4 (24%6==0 keeps ring aligned) -> bands chain; only
    // band 0 has a prologue.
    for (int band = 0; band < 7; ++band) {
        STAGE(band * 24, 8, 77)

        if (band == 0) {
#pragma unroll
            for (int k = 0; k < 5; ++k)
#pragma unroll
            for (int pr = 0; pr < 3; ++pr)
                win[k][pr] = *(const v2f*)(&smem[k * 196 + bb + 2 * pr]);
        }

        lds_off = 5 * 196 + bb;               // local row 5, this band
        for (int it = 0; it < 4; ++it) {      // rolled: small hot body
            USTEP6(0, 1, 1) USTEP6(1, 1, 1) USTEP6(2, 1, 1)
            USTEP6(3, 1, 1) USTEP6(4, 1, 1) USTEP6(5, 1, 1)
            pa += 6 * WW; pb += 6 * WW;       // next group's refill base
        }
    }
    // tail: u = 170..189 (LS 0..19), rows 168..191 at locals 0..23.
    STAGE(168, 7, 24)
    lds_off = 5 * 196 + bb;
    // LS 0..5 (u 170..175): GPF rows 176..181
    USTEP6(0, 1, 1) USTEP6(1, 1, 1) USTEP6(2, 1, 1)
    USTEP6(3, 1, 1) USTEP6(4, 1, 1) USTEP6(5, 1, 1)
    pa += 6 * WW; pb += 6 * WW;
    // LS 6..11 (u 176..181): GPF rows 182..187
    USTEP6(0, 1, 1) USTEP6(1, 1, 1) USTEP6(2, 1, 1)
    USTEP6(3, 1, 1) USTEP6(4, 1, 1) USTEP6(5, 1, 1)
    pa += 6 * WW; pb += 6 * WW;
    // LS 12..17 (u 182..187): GPF rows 188,189 only (LS<=13)
    USTEP6(0, 1, 1) USTEP6(1, 1, 1) USTEP6(2, 1, 0)
    USTEP6(3, 1, 0) USTEP6(4, 1, 0) USTEP6(5, 1, 0)
    // LS 18,19 (u 188,189): WPF local 23 at LS=18; none at LS=19
    USTEP6(0, 1, 0) USTEP6(1, 0, 0)
#undef USTEP6
#undef STAGE

    // stage edge buffer: buf i<6 -> abs row i-2 (OOB zero), i>=6 -> 188+(i-6).
    // Pads of rows 0..12 zero from init (never overwritten); row 12 = guard.
    __syncthreads();
    for (int i = 0; i < 12; ++i) {
        const int ar = (i < 6) ? (i - 2) : (188 + i - 6);
        const float val = (ar >= 0 && ar <= 191) ? x2g[(size_t)ar * WW + v] : 0.f;
        smem[i * 196 + 4 + v] = val;
    }
    __syncthreads();

    double* const gp = gram + (size_t)bg * (PP * PP);

// cw for (k=KQ, dj=DJ) at c=CVAL with that c's edge-row values XRA/XRB.
// Compile-time register indices; runtime select on p.
#define EPI_CW(KQ, DJ, CVAL, XRA, XRB)                                        \
    ({                                                                        \
        float ve_, vo_;                                                       \
        { const int pr_ = (DJ) >> 1, ln_ = (DJ) & 1;                          \
          const v2f m_ = ((CVAL) == 0) ? midA[(KQ) * 3 + pr_] : midB[(KQ) * 3 + pr_]; \
          ve_ = ln_ ? m_.y : m_.x; }                                          \
        { const int pr_ = ((DJ) + 1) >> 1, ln_ = ((DJ) + 1) & 1;              \
          const v2f m_ = ((CVAL) == 0) ? midA[(KQ) * 3 + pr_] : midB[(KQ) * 3 + pr_]; \
          vo_ = ln_ ? m_.y : m_.x; }                                          \
        float cw_ = p ? vo_ : ve_;                                            \
        cw_ = fmaf((XRA), smem[bufa * 196 + 2 + v + (DJ)], cw_);              \
        cw_ = fmaf((XRB), smem[bufb * 196 + 2 + v + (DJ)], cw_);              \
        cw_;                                                                  \
    })

#pragma unroll
    for (int i1 = 0; i1 < 3; ++i1) {
        const int ra = (i1 == 0) ? 0 : ((i1 == 1) ? 1 : 190);
        const int rb = (i1 == 0) ? 1 : ((i1 == 1) ? 190 : 191);
        const float xra0 = xa[(size_t)ra * WW + v];
        const float xrb0 = xa[(size_t)rb * WW + v];
        const float xra1 = xb[(size_t)ra * WW + v];
        const float xrb1 = xb[(size_t)rb * WW + v];
        // publish: high half -> red2 rows 0..95 (50 vals: c=0 then c=1);
        // threads 0,1 -> ebuf.
        if (v >= 96) {
            float* dst = red2 + (v - 96) * 51;
#pragma unroll
            for (int k = 0; k < 5; ++k) {
                const int bufa = (ra < 2) ? (ra + k) : (ra + k - 184);
                const int bufb = (rb < 2) ? (rb + k) : (rb + k - 184);
#pragma unroll
                for (int dj = 0; dj < 5; ++dj) {
                    dst[k * 5 + dj]      = EPI_CW(k, dj, 0, xra0, xrb0);
                    dst[25 + k * 5 + dj] = EPI_CW(k, dj, 1, xra1, xrb1);
                }
            }
        } else if (v < 2) {
            float* dst = ebuf + v * 50;
#pragma unroll
            for (int k = 0; k < 5; ++k) {
                const int bufa = (ra < 2) ? (ra + k) : (ra + k - 184);
                const int bufb = (rb < 2) ? (rb + k) : (rb + k - 184);
#pragma unroll
                for (int dj = 0; dj < 5; ++dj) {
                    dst[k * 5 + dj]      = EPI_CW(k, dj, 0, xra0, xrb0);
                    dst[25 + k * 5 + dj] = EPI_CW(k, dj, 1, xra1, xrb1);
                }
            }
        }
        __syncthreads();
        float e0 = 0.f, e1 = 0.f, e190 = 0.f, e191 = 0.f;
        if (v < 50) {
            e0   = ebuf[v];
            e1   = ebuf[50 + v];
            e190 = red2[94 * 51 + v];
            e191 = red2[95 * 51 + v];
        }
        __syncthreads();
        // merge (== old s=96 step): red2 row v = cw_high(v+96) + cw_low(v)
        if (v < 96) {
            float* dst = red2 + v * 51;
#pragma unroll
            for (int k = 0; k < 5; ++k) {
                const int bufa = (ra < 2) ? (ra + k) : (ra + k - 184);
                const int bufb = (rb < 2) ? (rb + k) : (rb + k - 184);
#pragma unroll
                for (int dj = 0; dj < 5; ++dj) {
                    dst[k * 5 + dj]      += EPI_CW(k, dj, 0, xra0, xrb0);
                    dst[25 + k * 5 + dj] += EPI_CW(k, dj, 1, xra1, xrb1);
                }
            }
        }
        __syncthreads();
        // tree reduce: 96 -> 48 -> ... -> 3 (same pairing per element as
        // the old per-c trees -> bit-identical sums)
#pragma unroll
        for (int s = 48; s >= 3; s >>= 1) {
            for (int idx = v; idx < s * 50; idx += 192) {
                const int vv = idx / 50, o = idx - vv * 50;
                red2[vv * 51 + o] += red2[(vv + s) * 51 + o];
            }
            __syncthreads();
        }
        if (v < 50) {
            const int c = v / 25;
            const int o = v - c * 25;
            if (c == 0 || bval) {
                const int di = o / 5 - 2, dj = o - (o / 5) * 5 - 2;
                const int i2 = i1 + di;
                if (i2 >= 0 && i2 <= 2) {
                    const float S = red2[0 * 51 + v] + red2[1 * 51 + v] + red2[2 * 51 + v];
                    const int c1 = (c == 0) ? c1a : c1b;
#pragma unroll
                    for (int j1 = 0; j1 < 3; ++j1) {
                        const int j2 = j1 + dj;
                        if (j2 < 0 || j2 > 2) continue;
                        const float W = S - ((j1 == 0) ? (e190 + e191)
                                          : (j1 == 1) ? (e0 + e191)
                                                      : (e0 + e1));
                        const int pp = c1 * 9 + i1 * 3 + j1;
                        const int qq = c2 * 9 + i2 * 3 + j2;
                        gp[pp * PP + qq] = (double)W;
                        if (c1 != c2) gp[qq * PP + pp] = (double)W;
                    }
                }
            }
        }
        __syncthreads();   // red2 reused by next i1
    }
#undef EPI_CW
}

// ---------------------------------------------------------------------------
// Kernel 2: per-group argmin (f64 d2, first-min tiebreak), bincount over both
// batches, stable top-3 (smallest index on count ties, matching lax.top_k).
// ---------------------------------------------------------------------------
__global__ __launch_bounds__(320) void topk_kernel(const double* __restrict__ gram,
                                                   float* __restrict__ pf,
                                                   int* __restrict__ pi)
{
    const int g = blockIdx.x;
    __shared__ double sdiag[2][PP];
    __shared__ int counts[PP];
    const int tid = threadIdx.x;
    if (tid < PP) counts[tid] = 0;
    if (tid < 2 * PP) {
        const int b = tid / PP, p = tid % PP;
        const double* gb = gram + (size_t)(b * 16 + g) * (PP * PP);
        sdiag[b][p] = gb[p * PP + p];
    }
    __syncthreads();
    if (tid < 2 * PP) {
        const int b = tid / PP, p = tid % PP;
        const double* row = gram + ((size_t)(b * 16 + g) * PP + p) * PP;
        const double sp = sdiag[b][p];
        double best = 1e300;
        int bi = 0;
        for (int q = 0; q < PP; ++q) {
            if (q == p) continue;
            const double d2 = sp + sdiag[b][q] - 2.0 * row[q];
            if (d2 < best) { best = d2; bi = q; }   // strict < : first occurrence
        }
        atomicAdd(&counts[bi], 1);
    }
    __syncthreads();
    if (tid == 0) {
        int sel[3], cv[3];
        for (int o = 0; o < 3; ++o) {
            int bc = -1, bp = 0;
            for (int p = 0; p < PP; ++p) {
                bool taken = false;
                for (int u = 0; u < o; ++u) if (sel[u] == p) taken = true;
                if (!taken && counts[p] > bc) { bc = counts[p]; bp = p; } // > keeps lowest idx
            }
            sel[o] = bp; cv[o] = bc;
        }
        const int tot = cv[0] + cv[1] + cv[2];
        for (int o = 0; o < 3; ++o) {
            pf[g * 4 + o] = (float)cv[o];
            pi[g * 4 + o] = sel[o];
        }
        pf[g * 4 + 3] = (float)tot;
    }
}

// ---------------------------------------------------------------------------
// Kernel 3: fused scale->floor->fold stencil. Division via Markstein 2-fma
// (== __fdiv_rn; margin argument: total<=288, quotients >=2^-34 rel from any
// f32 midpoint, refinement error ~2^-47 -> identical rounding; passed r16).
// Interior path pk-packed over q-pairs: per-component v2f mul/fma are the
// SAME IEEE f32 ops in the same order -> bit-exact vs scalar. Edge path
// scalar, unchanged. Interior/edge split by block range in one kernel.
// ---------------------------------------------------------------------------
__device__ __forceinline__ void motif_quad_pk(const float* __restrict__ x,
                                              const float* __restrict__ pf,
                                              const int* __restrict__ pi,
                                              float* __restrict__ out,
                                              int b, int ch, int h, int w0)
{
    const int g = ch >> 4;
    const size_t base = ((size_t)(b * NC + ch)) * (HH * WW);
    const float4 xv4 = *(const float4*)(x + base + (size_t)h * WW + w0);
    const v2f xp01 = (v2f){xv4.x, xv4.y};
    const v2f xp23 = (v2f){xv4.z, xv4.w};
    v2f acc01 = (v2f){0.f, 0.f}, acc23 = (v2f){0.f, 0.f};
    const float total = pf[g * 4 + 3];
    const float rcp = (float)(1.0 / (double)total);   // == RN32(1/total)
    const v2f rcp2 = (v2f){rcp, rcp};
    const v2f ntot2 = (v2f){-total, -total};

#pragma unroll
    for (int o = 0; o < 3; ++o) {
        const int p = pi[g * 4 + o];
        const float cff = pf[g * 4 + o];
        const v2f cf2 = (v2f){cff, cff};
        const int co = p / 9;
        const int kk = p - co * 9;
        const int io = kk / 3, jo = kk - (kk / 3) * 3;
        const float* Rb = x + ((size_t)(b * NC + g * CG + co)) * (HH * WW);
#pragma unroll
        for (int i = 0; i < 3; ++i) {
            const float* row = Rb + (size_t)(h - i + io) * WW;
            float rv[6];
#pragma unroll
            for (int u = 0; u < 6; ++u)
                rv[u] = row[w0 - 2 + jo + u];
#pragma unroll
            for (int j = 0; j < 3; ++j) {
                const v2f r01 = (v2f){rv[2 - j], rv[3 - j]};
                const v2f r23 = (v2f){rv[4 - j], rv[5 - j]};
                const v2f t1a = xp01 * r01;               // == __fmul_rn x2
                const v2f t1b = xp23 * r23;
                const v2f t2a = t1a * cf2;
                const v2f t2b = t1b * cf2;
                const v2f q0a = t2a * rcp2;
                const v2f q0b = t2b * rcp2;
                const v2f rra = __builtin_elementwise_fma(ntot2, q0a, t2a);
                const v2f rrb = __builtin_elementwise_fma(ntot2, q0b, t2b);
                const v2f qfa = __builtin_elementwise_fma(rra, rcp2, q0a);
                const v2f qfb = __builtin_elementwise_fma(rrb, rcp2, q0b);
                acc01.x += floorf(qfa.x);
                acc01.y += floorf(qfa.y);
                acc23.x += floorf(qfb.x);
                acc23.y += floorf(qfb.y);
            }
        }
    }
    float4 ov = make_float4(acc01.x, acc01.y, acc23.x, acc23.y);
    *(float4*)(out + base + (size_t)h * WW + w0) = ov;
}

__device__ __forceinline__ void motif_quad_edge(const float* __restrict__ x,
                                                const float* __restrict__ pf,
                                                const int* __restrict__ pi,
                                                float* __restrict__ out,
                                                int b, int ch, int h, int w0)
{
    const int g = ch >> 4;
    const size_t base = ((size_t)(b * NC + ch)) * (HH * WW);
    const float4 xv4 = *(const float4*)(x + base + (size_t)h * WW + w0);
    const float xs[4] = {xv4.x, xv4.y, xv4.z, xv4.w};
    float acc[4] = {0.f, 0.f, 0.f, 0.f};
    const float total = pf[g * 4 + 3];
    const float rcp = (float)(1.0 / (double)total);

#pragma unroll
    for (int o = 0; o < 3; ++o) {
        const int p = pi[g * 4 + o];
        const float cff = pf[g * 4 + o];
        const int co = p / 9;
        const int kk = p - co * 9;
        const int io = kk / 3, jo = kk - (kk / 3) * 3;
        const float* Rb = x + ((size_t)(b * NC + g * CG + co)) * (HH * WW);
#pragma unroll
        for (int i = 0; i < 3; ++i) {
            const int ho = h - i;
            const bool rowok = (ho >= 0) && (ho < HO);
            int hr = ho + io;
            hr = hr < 0 ? 0 : (hr > HH - 1 ? HH - 1 : hr);
            const float* row = Rb + (size_t)hr * WW;
            float rv[6];
#pragma unroll
            for (int u = 0; u < 6; ++u) {
                int col = w0 - 2 + jo + u;
                col = col < 0 ? 0 : (col > WW - 1 ? WW - 1 : col);
                rv[u] = row[col];
            }
#pragma unroll
            for (int j = 0; j < 3; ++j)
#pragma unroll
            for (int q = 0; q < 4; ++q) {
                const float r2 = rv[q - j + 2];
                const float t1 = xs[q] * r2;
                const float t2 = t1 * cff;
                const float q0 = t2 * rcp;
                const float rr = fmaf(-total, q0, t2);
                const float qf = fmaf(rr, rcp, q0);       // == __fdiv_rn
                const float vfl = floorf(qf);
                const int wo = w0 + q - j;
                const bool ok = rowok && (wo >= 0) && (wo < HO);
                acc[q] += ok ? vfl : 0.f;
            }
        }
    }
    float4 ov = make_float4(acc[0], acc[1], acc[2], acc[3]);
    *(float4*)(out + base + (size_t)h * WW + w0) = ov;
}

#define NBLK_INT 17296   // 2*256*188*46/256
#define NBLK_EDGE 1136   // 2*256*568/256

__global__ __launch_bounds__(256) void out_kernel(const float* __restrict__ x,
                                                  const float* __restrict__ pf,
                                                  const int* __restrict__ pi,
                                                  float* __restrict__ out)
{
    const int bid = blockIdx.x;
    if (bid < NBLK_INT) {
        // interior: h in [2,189], w4 in [1,46] -> no clamps/masks anywhere.
        const int gid = bid * 256 + threadIdx.x;
        const int w4i = gid % 46;
        int t = gid / 46;
        const int h = 2 + t % 188; t /= 188;
        const int ch = t & 255;
        const int b = t >> 8;
        motif_quad_pk(x, pf, pi, out, b, ch, h, (w4i + 1) * 4);
    } else {
        // edge: 568 quads per (b,ch): h in {0,1,190,191} x all 48 w4, plus
        // h in [2,189] x w4 in {0,47}.
        const int gid = (bid - NBLK_INT) * 256 + threadIdx.x;
        const int e = gid % 568;
        int t = gid / 568;
        const int ch = t & 255;
        const int b = t >> 8;
        int h, w4;
        if (e < 192) {
            const int hs = e / 48;
            h = (hs < 2) ? hs : 188 + hs;     // 0,1,190,191
            w4 = e % 48;
        } else {
            const int e2 = e - 192;
            h = 2 + (e2 >> 1);
            w4 = (e2 & 1) ? 47 : 0;
        }
        motif_quad_edge(x, pf, pi, out, b, ch, h, w4 * 4);
    }
}

// ---------------------------------------------------------------------------
extern "C" void kernel_launch(void* const* d_in, const int* in_sizes, int n_in,
                              void* d_out, int out_size, void* d_ws, size_t ws_size,
                              hipStream_t stream)
{
    const float* x = (const float*)d_in[0];
    float* out = (float*)d_out;

    double* gram = (double*)d_ws;
    const size_t gram_bytes = (size_t)32 * PP * PP * sizeof(double); // 5,308,416 B
    float* pf = (float*)((char*)d_ws + gram_bytes);
    int* pi = (int*)((char*)d_ws + gram_bytes + 256);

    gram_kernel<<<2304, 192, 0, stream>>>(x, gram);
    topk_kernel<<<16, 320, 0, stream>>>(gram, pf, pi);
    out_kernel<<<NBLK_INT + NBLK_EDGE, 256, 0, stream>>>(x, pf, pi, out);
}